// Round 8
// baseline (80.490 us; speedup 1.0000x reference)
//
#include <hip/hip_runtime.h>

// ThinPlateSpline via two-phase MFMA (flash-attention pattern):
//   Phase 1: R2[16q x 16c] = MFMA(A_u, B_c)   (bf16 hi/lo split, K=13 of 32)
//            r2 = |u|^2 + |c|^2 - 2 u.c
//   Phase 2: kk = sqrt(r2) * log2(r2)  (hw trans, the per-pair floor),
//            kk -> bf16 -> LDS (C-layout -> A-layout), OUT += MFMA(KK, W)
//   C = 0.5*ln2 folded into packed W. Poly term added in the epilogue.
//
// Block = 512 thr = 8 waves = one 16-query tile x 8-way n-split; grid 1024
// = 4 blocks/CU -> 8 waves/SIMD. In-block fragment-preserving reduction ->
// no atomics, no memset. Control/W data pre-packed to d_ws (L2-resident).

typedef __attribute__((ext_vector_type(8))) short short8;
typedef __attribute__((ext_vector_type(4))) float float4v;

#define WT_STRIDE 4104  // elements per w_t row (4096 + 8 for bank spread)

__device__ inline unsigned short bf16rn(float x) {
    unsigned u = __float_as_uint(x);
    return (unsigned short)((u + 0x7FFFu + ((u >> 16) & 1u)) >> 16);
}
__device__ inline float bf16tof(unsigned short h) {
    return __uint_as_float(((unsigned)h) << 16);
}

// Per control j: 16 bf16 slots pairing with the query A-vector:
//  A: [ah0,ah1,ah2, ah0,ah1,ah2, al0,al1, | al2, usqh,usql, 1,1, 0,0,0]
//  B: [bh0,bh1,bh2, bl0,bl1,bl2, bh0,bh1, | bh2, 1,1, csqh,csql, 0,0,0]
__global__ void pack_kernel(const float* __restrict__ cp,
                            const float* __restrict__ w,
                            unsigned short* __restrict__ pack,
                            unsigned short* __restrict__ wt, int n) {
    const int j = blockIdx.x * blockDim.x + threadIdx.x;
    if (j >= n) return;
    const float C = 0.34657359027997264f;  // 0.5 * ln(2)
    const float cx = cp[j * 3 + 0], cy = cp[j * 3 + 1], cz = cp[j * 3 + 2];
    const unsigned short bh0 = bf16rn(cx), bh1 = bf16rn(cy), bh2 = bf16rn(cz);
    const unsigned short bl0 = bf16rn(cx - bf16tof(bh0));
    const unsigned short bl1 = bf16rn(cy - bf16tof(bh1));
    const unsigned short bl2 = bf16rn(cz - bf16tof(bh2));
    const float csq = fmaf(cx, cx, fmaf(cy, cy, cz * cz));
    const unsigned short ch = bf16rn(csq), cl = bf16rn(csq - bf16tof(ch));
    const unsigned short one = 0x3F80;
    unsigned short s[16] = {bh0, bh1, bh2, bl0, bl1, bl2, bh0, bh1,
                            bh2, one, one, ch, cl, 0, 0, 0};
#pragma unroll
    for (int t = 0; t < 16; ++t) pack[j * 16 + t] = s[t];
    wt[0 * WT_STRIDE + j] = bf16rn(C * w[j * 3 + 0]);
    wt[1 * WT_STRIDE + j] = bf16rn(C * w[j * 3 + 1]);
    wt[2 * WT_STRIDE + j] = bf16rn(C * w[j * 3 + 2]);
    wt[3 * WT_STRIDE + j] = 0;  // zero row for padded N-lanes
}

#define BLK 512
#define NSPLIT 8  // waves per block = n-splits

__global__ __launch_bounds__(BLK) void tps_mfma(
    const float* __restrict__ u,            // (batch, 3)
    const unsigned short* __restrict__ pack,// (n, 16) bf16 slots
    const unsigned short* __restrict__ wt,  // (4, WT_STRIDE) bf16
    const float* __restrict__ poly,         // (4, 3)
    float* __restrict__ out,                // (batch, 3)
    int batch, int n)
{
    __shared__ unsigned short kk[NSPLIT][16 * 40];  // per-wave [16 q][40] bf16
    __shared__ float red[NSPLIT][64][4];            // frag-layout partials

    const int tid  = threadIdx.x;
    const int lane = tid & 63;
    const int wv   = tid >> 6;       // 0..7 = n-split
    const int col  = lane & 15;
    const int quad = lane >> 4;

    const int qt = blockIdx.x;       // query tile (16 queries)

    // ---- A1 fragment (constant per wave): query hi/lo-split vector ----
    const int q_a = qt * 16 + col;
    const float ax_ = u[q_a * 3 + 0], ay_ = u[q_a * 3 + 1], az_ = u[q_a * 3 + 2];
    const float m2x = -2.f * ax_, m2y = -2.f * ay_, m2z = -2.f * az_;
    const unsigned short h0 = bf16rn(m2x), h1 = bf16rn(m2y), h2 = bf16rn(m2z);
    const unsigned short l0 = bf16rn(m2x - bf16tof(h0));
    const unsigned short l1 = bf16rn(m2y - bf16tof(h1));
    const unsigned short l2 = bf16rn(m2z - bf16tof(h2));
    const float usq = fmaf(ax_, ax_, fmaf(ay_, ay_, az_ * az_));
    const unsigned short sh = bf16rn(usq), sl = bf16rn(usq - bf16tof(sh));
    const unsigned short one = 0x3F80;

    short8 a1 = {0, 0, 0, 0, 0, 0, 0, 0};
    if (quad == 0) {
        a1[0] = (short)h0; a1[1] = (short)h1; a1[2] = (short)h2;
        a1[3] = (short)h0; a1[4] = (short)h1; a1[5] = (short)h2;
        a1[6] = (short)l0; a1[7] = (short)l1;
    } else if (quad == 1) {
        a1[0] = (short)l2; a1[1] = (short)sh; a1[2] = (short)sl;
        a1[3] = (short)one; a1[4] = (short)one;
    }

    const float4v zero4 = {0.f, 0.f, 0.f, 0.f};
    float4v acc = {0.f, 0.f, 0.f, 0.f};

    const int cstart = wv * (n / NSPLIT);
    const int cend   = cstart + (n / NSPLIT);
    unsigned short* kkw = &kk[wv][(quad * 4) * 40 + col];

    for (int cb = cstart; cb < cend; cb += 32) {
        // ---- Phase 1: two 16x16 r2 tiles ----
        short8 b0 = {0, 0, 0, 0, 0, 0, 0, 0};
        short8 b1 = {0, 0, 0, 0, 0, 0, 0, 0};
        if (quad < 2) {  // k=16..31 slots are zero; skip their loads
            b0 = *(const short8*)(pack + (cb + col) * 16 + quad * 8);
            b1 = *(const short8*)(pack + (cb + 16 + col) * 16 + quad * 8);
        }
        float4v r2a = __builtin_amdgcn_mfma_f32_16x16x32_bf16(a1, b0, zero4, 0, 0, 0);
        float4v r2b = __builtin_amdgcn_mfma_f32_16x16x32_bf16(a1, b1, zero4, 0, 0, 0);

        // ---- Phase 2a: kk = sqrt(r2)*log2(r2), bf16-truncate, to LDS ----
#pragma unroll
        for (int i = 0; i < 4; ++i) {
            const float va = fmaxf(r2a[i], 1e-30f);
            const float vb = fmaxf(r2b[i], 1e-30f);
            const float ka = __builtin_amdgcn_sqrtf(va) * __builtin_amdgcn_logf(va);
            const float kb = __builtin_amdgcn_sqrtf(vb) * __builtin_amdgcn_logf(vb);
            kkw[i * 40 + 0]  = (unsigned short)(__float_as_uint(ka) >> 16);
            kkw[i * 40 + 16] = (unsigned short)(__float_as_uint(kb) >> 16);
        }

        // ---- Phase 2b: OUT += KK[16x32] @ W[32x16] ----
        short8 a2 = *(const short8*)(&kk[wv][col * 40 + quad * 8]);
        const int nr = col < 3 ? col : 3;  // rows >=3 of wt are zeros
        short8 wf = *(const short8*)(wt + nr * WT_STRIDE + cb + quad * 8);
        acc = __builtin_amdgcn_mfma_f32_16x16x32_bf16(a2, wf, acc, 0, 0, 0);
    }

    // ---- In-block reduction across the 8 n-split waves ----
    red[wv][lane][0] = acc[0];
    red[wv][lane][1] = acc[1];
    red[wv][lane][2] = acc[2];
    red[wv][lane][3] = acc[3];
    __syncthreads();

    if (wv == 0 && col < 3) {
#pragma unroll
        for (int i = 0; i < 4; ++i) {
            float s = 0.f;
#pragma unroll
            for (int w2 = 0; w2 < NSPLIT; ++w2) s += red[w2][lane][i];
            const int q = qt * 16 + quad * 4 + i;  // D row = quad*4 + reg
            const float px = u[q * 3 + 0], py = u[q * 3 + 1], pz = u[q * 3 + 2];
            s += poly[col] + px * poly[3 + col] + py * poly[6 + col]
                           + pz * poly[9 + col];
            out[q * 3 + col] = s;
        }
    }
}

extern "C" void kernel_launch(void* const* d_in, const int* in_sizes, int n_in,
                              void* d_out, int out_size, void* d_ws, size_t ws_size,
                              hipStream_t stream) {
    const float* u    = (const float*)d_in[0];  // (batch,3)
    const float* cp   = (const float*)d_in[1];  // (n,3)
    const float* w    = (const float*)d_in[2];  // (n,3)
    const float* poly = (const float*)d_in[3];  // (4,3)
    float* out = (float*)d_out;

    const int batch = in_sizes[0] / 3;  // 16384
    const int n     = in_sizes[1] / 3;  // 4096

    unsigned short* pack = (unsigned short*)d_ws;            // n*16 bf16 = 128 KB
    unsigned short* wt   = pack + (size_t)n * 16;            // 4*WT_STRIDE bf16

    pack_kernel<<<(n + 255) / 256, 256, 0, stream>>>(cp, w, pack, wt, n);

    dim3 block(BLK);
    dim3 grid(batch / 16);  // 1024 blocks = one 16-query tile each
    tps_mfma<<<grid, block, 0, stream>>>(u, pack, wt, poly, out, batch, n);
}